// Round 3
// baseline (170.823 us; speedup 1.0000x reference)
//
#include <hip/hip_runtime.h>
#include <hip/hip_bf16.h>
#include <math.h>

#define NB 32768
#define DD 128
#define HH 512
#define EE 16
#define TM 64
#define HC 64
#define NCH (HH / HC)

typedef __attribute__((ext_vector_type(8))) short short8;
typedef __attribute__((ext_vector_type(4))) float f32x4;

__device__ __forceinline__ unsigned short f2bf(float f) {
  union { float f; unsigned u; } v; v.f = f;
  unsigned r = v.u + 0x7fffu + ((v.u >> 16) & 1u);
  return (unsigned short)(r >> 16);
}

// Abramowitz-Stegun 7.1.26 erf, |eps| <= 1.5e-7; v_rcp (1 ULP) instead of IEEE div
__device__ __forceinline__ float fast_erf(float z) {
  float a = fabsf(z);
  float t = __builtin_amdgcn_rcpf(1.0f + 0.3275911f * a);
  float y = t * (0.254829592f + t * (-0.284496736f + t * (1.421413741f +
            t * (-1.453152027f + t * 1.061405429f))));
  float r = 1.0f - y * __expf(-a * a);
  return z < 0.0f ? -r : r;
}

// ---------------- fused prep: gate (blocks 0..511) + weight transpose (512..1023) ----------
__global__ __launch_bounds__(256) void prep_kernel(
    const float* __restrict__ x, const float* __restrict__ wg,
    const float* __restrict__ bg, const float* __restrict__ w1,
    const float* __restrict__ w2, int* __restrict__ counts,
    int* __restrict__ rows, unsigned short* __restrict__ w1T,
    unsigned short* __restrict__ w2T) {
  __shared__ __align__(16) char smem[50816];
  int tid = threadIdx.x;

  if (blockIdx.x >= 512) {
    // ---- 64x64 fp32 tile transpose -> bf16 ----
    float (*tile)[65] = (float (*)[65])smem;
    int tp = blockIdx.x - 512;
    const float* src; unsigned short* dst; int S, Sd;
    if (tp < 256) {
      int e = tp >> 4, t2 = tp & 15;
      int d0 = (t2 >> 3) * 64, h0 = (t2 & 7) * 64;
      src = w1 + (size_t)e * DD * HH + (size_t)d0 * HH + h0; S = HH;
      dst = w1T + (size_t)e * HH * DD + (size_t)h0 * DD + d0; Sd = DD;
    } else {
      int t = tp - 256;
      int e = t >> 4, t2 = t & 15;
      int h0 = (t2 >> 1) * 64, d0 = (t2 & 1) * 64;
      src = w2 + (size_t)e * HH * DD + (size_t)h0 * DD + d0; S = DD;
      dst = w2T + (size_t)e * DD * HH + (size_t)d0 * HH + h0; Sd = HH;
    }
    #pragma unroll
    for (int i = 0; i < 4; ++i) {
      int u = tid + i * 256, r = u >> 4, c = (u & 15) * 4;
      float4 v = *(const float4*)(src + (size_t)r * S + c);
      tile[r][c + 0] = v.x; tile[r][c + 1] = v.y;
      tile[r][c + 2] = v.z; tile[r][c + 3] = v.w;
    }
    __syncthreads();
    #pragma unroll
    for (int i = 0; i < 4; ++i) {
      int u = tid + i * 256, tr = u >> 4, tc = (u & 15) * 4;
      ushort4 p;
      p.x = f2bf(tile[tc + 0][tr]); p.y = f2bf(tile[tc + 1][tr]);
      p.z = f2bf(tile[tc + 2][tr]); p.w = f2bf(tile[tc + 3][tr]);
      *(ushort4*)(dst + (size_t)tr * Sd + tc) = p;
    }
    return;
  }

  // ---- gating: fp64 logits + block-aggregated bucket scatter ----
  float  (*sx)[132] = (float (*)[132])smem;
  double (*swg)[EE] = (double (*)[EE])(smem + 33792);
  int* lcnt  = (int*)(smem + 50176);
  int* gbase = lcnt + EE;
  int* lslot = gbase + EE;
  int* lexp  = lslot + 64;

  int base = blockIdx.x * 64;
  if (tid < EE) lcnt[tid] = 0;
  for (int i = tid; i < DD * EE; i += 256) swg[i >> 4][i & 15] = (double)wg[i];
  {
    int r = tid >> 2, c0 = (tid & 3) * 32;
    const float4* src = (const float4*)(x + (size_t)(base + r) * DD + c0);
    #pragma unroll
    for (int i = 0; i < 8; ++i)
      *(float4*)&sx[r][c0 + i * 4] = src[i];
  }
  __syncthreads();

  int r = tid >> 2;
  int e0 = (tid & 3) * 4;
  double acc[4];
  #pragma unroll
  for (int j = 0; j < 4; ++j) acc[j] = (double)bg[e0 + j];

  #pragma unroll 4
  for (int d = 0; d < DD; ++d) {
    double xv = (double)sx[r][d];
    #pragma unroll
    for (int j = 0; j < 4; ++j)
      acc[j] += xv * swg[d][e0 + j];
  }

  int beste = 0; double bestv = acc[0];
  #pragma unroll
  for (int j = 1; j < 4; ++j)
    if (acc[j] > bestv) { bestv = acc[j]; beste = j; }
  int ge = e0 + beste;

  #pragma unroll
  for (int off = 1; off < 4; off <<= 1) {
    double ov = __shfl_xor(bestv, off);
    int oe = __shfl_xor(ge, off);
    if (ov > bestv || (ov == bestv && oe < ge)) { bestv = ov; ge = oe; }
  }

  if ((tid & 3) == 0) {
    lslot[r] = atomicAdd(&lcnt[ge], 1);
    lexp[r] = ge;
  }
  __syncthreads();
  if (tid < EE && lcnt[tid] > 0)
    gbase[tid] = atomicAdd(&counts[tid], lcnt[tid]);
  __syncthreads();
  if ((tid & 3) == 0) {
    int e2 = lexp[r];
    rows[e2 * NB + gbase[e2] + lslot[r]] = base + r;
  }
}

// ---------------- grouped expert GEMM: out[r] = gelu(x[r]@w1[e]) @ w2[e] ----------------
// v4: __launch_bounds__(256,2) gives the register allocator room (R2's 64-VGPR fit sank
//     the prefetch loads -> serial L2 latency every chunk). HC=64 halves barrier count.
//     sH stride 72 breaks the 4-way gelu-write bank conflict. rcp-erf cuts ~10 VALU/gelu.
// Swizzle invariant (write == read): element (row, col) short-index =
//   row*C + ((col>>3) ^ (row&7))*8 + (col&7)   for C=128 (sW1) and C=64 (sW2).
__global__ __launch_bounds__(256, 2) void moe_gemm(
    const float* __restrict__ x, const unsigned short* __restrict__ w1T,
    const unsigned short* __restrict__ w2T, const int* __restrict__ counts,
    const int* __restrict__ rows, float* __restrict__ out) {
  int e = blockIdx.x;
  int cnt = counts[e];
  int base = blockIdx.y * TM;
  if (base >= cnt) return;

  __shared__ unsigned short sW1[2][HC][DD];   // [h][d], swizzled, 32 KB
  __shared__ unsigned short sW2[2][DD][HC];   // [d][h], swizzled, 32 KB
  __shared__ unsigned short sH[TM][72];       // [m][h], padded, wave-private rows, 9 KB

  int tid = threadIdx.x;
  int wv = tid >> 6, l = tid & 63;
  int lm = l & 15, q = l >> 4;

  // X A-fragments in registers: xa[ks] holds X[m][k = ks*32 + q*8 + j]
  short8 xa[4];
  {
    int ridx = base + wv * 16 + lm; if (ridx >= cnt) ridx = cnt - 1;
    int grow = rows[e * NB + ridx];
    const float* xr = x + (size_t)grow * DD + q * 8;
    #pragma unroll
    for (int ks = 0; ks < 4; ++ks) {
      f32x4 v0 = *(const f32x4*)(xr + ks * 32);
      f32x4 v1 = *(const f32x4*)(xr + ks * 32 + 4);
      short8 a;
      a[0] = f2bf(v0[0]); a[1] = f2bf(v0[1]); a[2] = f2bf(v0[2]); a[3] = f2bf(v0[3]);
      a[4] = f2bf(v1[0]); a[5] = f2bf(v1[1]); a[6] = f2bf(v1[2]); a[7] = f2bf(v1[3]);
      xa[ks] = a;
    }
  }

  // staging geometry: sW1 4x uint4/thread (rows u>>4 + 16k), sW2 4x uint4 (rows u>>2, +64)
  int r1s = tid >> 4, s1s = tid & 15;
  int sl1 = (s1s ^ (r1s & 7)) * 8;            // (r+16k)&7 == r&7
  int r2s = tid >> 2, s2s = tid & 3;          // two slots 2*s2s, 2*s2s+1 per row
  int sl2a = ((2 * s2s)     ^ (r2s & 7)) * 8; // (r+64)&7 == r&7
  int sl2b = ((2 * s2s + 1) ^ (r2s & 7)) * 8;

  const unsigned short* w1e = w1T + (size_t)e * HH * DD;
  const unsigned short* w2e = w2T + (size_t)e * DD * HH;

  // prologue: stage chunk 0 into buffer 0
  {
    #pragma unroll
    for (int k = 0; k < 4; ++k) {
      uint4 a = *(const uint4*)(w1e + (size_t)tid * 8 + (size_t)k * 2048);
      *(uint4*)&sW1[0][r1s + 16 * k][sl1] = a;
    }
    uint4 b0 = *(const uint4*)(w2e + (size_t)r2s * HH + s2s * 16);
    uint4 b1 = *(const uint4*)(w2e + (size_t)r2s * HH + s2s * 16 + 8);
    uint4 b2 = *(const uint4*)(w2e + (size_t)(r2s + 64) * HH + s2s * 16);
    uint4 b3 = *(const uint4*)(w2e + (size_t)(r2s + 64) * HH + s2s * 16 + 8);
    *(uint4*)&sW2[0][r2s][sl2a]      = b0;
    *(uint4*)&sW2[0][r2s][sl2b]      = b1;
    *(uint4*)&sW2[0][r2s + 64][sl2a] = b2;
    *(uint4*)&sW2[0][r2s + 64][sl2b] = b3;
  }
  __syncthreads();

  f32x4 acc2[8];
  #pragma unroll
  for (int n = 0; n < 8; ++n) acc2[n] = (f32x4){0.f, 0.f, 0.f, 0.f};

  for (int hc = 0; hc < NCH; ++hc) {
    int b = hc & 1;

    // issue next chunk's global loads early (regs live across compute -> latency hidden)
    uint4 pa[4], pb[4];
    if (hc + 1 < NCH) {
      const unsigned short* w1c = w1e + (size_t)(hc + 1) * HC * DD;
      const unsigned short* w2c = w2e + (size_t)(hc + 1) * HC;
      #pragma unroll
      for (int k = 0; k < 4; ++k)
        pa[k] = *(const uint4*)(w1c + (size_t)tid * 8 + (size_t)k * 2048);
      pb[0] = *(const uint4*)(w2c + (size_t)r2s * HH + s2s * 16);
      pb[1] = *(const uint4*)(w2c + (size_t)r2s * HH + s2s * 16 + 8);
      pb[2] = *(const uint4*)(w2c + (size_t)(r2s + 64) * HH + s2s * 16);
      pb[3] = *(const uint4*)(w2c + (size_t)(r2s + 64) * HH + s2s * 16 + 8);
    }

    // GEMM1: hidden(16x64 per wave) = X(16x128, regs) @ W1chunk(128x64)
    f32x4 acc1[4];
    #pragma unroll
    for (int n = 0; n < 4; ++n) acc1[n] = (f32x4){0.f, 0.f, 0.f, 0.f};
    #pragma unroll
    for (int ks = 0; ks < 4; ++ks) {
      #pragma unroll
      for (int n = 0; n < 4; ++n) {
        int row = n * 16 + lm;
        int sl = ((ks * 4 + q) ^ (row & 7)) * 8;
        short8 bfr = *(const short8*)&sW1[b][row][sl];
        acc1[n] = __builtin_amdgcn_mfma_f32_16x16x32_bf16(xa[ks], bfr, acc1[n], 0, 0, 0);
      }
    }
    // gelu -> bf16 -> sH (wave-private rows; same-wave lgkmcnt orders RAW)
    #pragma unroll
    for (int n = 0; n < 4; ++n) {
      #pragma unroll
      for (int rr = 0; rr < 4; ++rr) {
        float v = acc1[n][rr];
        float g = 0.5f * v * (1.0f + fast_erf(v * 0.70710678118654752f));
        sH[wv * 16 + q * 4 + rr][n * 16 + lm] = f2bf(g);
      }
    }
    // GEMM2: out(16x128 per wave) += H(16x64) @ W2chunk(64x128)
    #pragma unroll
    for (int ks = 0; ks < 2; ++ks) {
      int kk = ks * 32 + q * 8;
      short8 a = *(const short8*)&sH[wv * 16 + lm][kk];
      #pragma unroll
      for (int n = 0; n < 8; ++n) {
        int row = n * 16 + lm;
        int sl = ((ks * 4 + q) ^ (row & 7)) * 8;
        short8 bfr = *(const short8*)&sW2[b][row][sl];
        acc2[n] = __builtin_amdgcn_mfma_f32_16x16x32_bf16(a, bfr, acc2[n], 0, 0, 0);
      }
    }

    // write prefetched chunk into the other buffer (loads landed during compute)
    if (hc + 1 < NCH) {
      #pragma unroll
      for (int k = 0; k < 4; ++k)
        *(uint4*)&sW1[b ^ 1][r1s + 16 * k][sl1] = pa[k];
      *(uint4*)&sW2[b ^ 1][r2s][sl2a]      = pb[0];
      *(uint4*)&sW2[b ^ 1][r2s][sl2b]      = pb[1];
      *(uint4*)&sW2[b ^ 1][r2s + 64][sl2a] = pb[2];
      *(uint4*)&sW2[b ^ 1][r2s + 64][sl2b] = pb[3];
    }
    __syncthreads();
  }

  // epilogue: scatter rows (score == 1.0 for top-1 softmax)
  #pragma unroll
  for (int rr = 0; rr < 4; ++rr) {
    int ml = wv * 16 + q * 4 + rr;
    int ridx = base + ml;
    if (ridx < cnt) {
      int grow = rows[e * NB + ridx];
      float* op = out + (size_t)grow * DD + lm;
      #pragma unroll
      for (int n = 0; n < 8; ++n) op[n * 16] = acc2[n][rr];
    }
  }
}

extern "C" void kernel_launch(void* const* d_in, const int* in_sizes, int n_in,
                              void* d_out, int out_size, void* d_ws, size_t ws_size,
                              hipStream_t stream) {
  const float* x  = (const float*)d_in[0];
  const float* w1 = (const float*)d_in[1];
  const float* w2 = (const float*)d_in[2];
  const float* wg = (const float*)d_in[3];
  const float* bg = (const float*)d_in[4];
  float* out = (float*)d_out;

  // workspace: [0,64) counts ; [1024, +2MB) rows ; w1T bf16 2MB ; w2T bf16 2MB
  int* counts = (int*)d_ws;
  int* rows   = (int*)((char*)d_ws + 1024);
  unsigned short* w1T = (unsigned short*)((char*)d_ws + 1024 + (size_t)EE * NB * 4);
  unsigned short* w2T = w1T + (size_t)EE * HH * DD;

  hipMemsetAsync(d_ws, 0, 64, stream);
  hipLaunchKernelGGL(prep_kernel, dim3(1024), dim3(256), 0, stream,
                     x, wg, bg, w1, w2, counts, rows, w1T, w2T);
  hipLaunchKernelGGL(moe_gemm, dim3(EE, NB / TM), dim3(256), 0, stream,
                     x, w1T, w2T, counts, rows, out);
}

// Round 4
// 135.222 us; speedup vs baseline: 1.2633x; 1.2633x over previous
//
#include <hip/hip_runtime.h>
#include <hip/hip_bf16.h>
#include <math.h>

#define NB 32768
#define DD 128
#define HH 512
#define EE 16
#define TM 64
#define HC 64
#define NCH (HH / HC)

typedef __attribute__((ext_vector_type(8))) short short8;
typedef __attribute__((ext_vector_type(4))) float f32x4;
typedef __attribute__((address_space(1))) const unsigned short gc_us;
typedef __attribute__((address_space(3))) unsigned short lds_us;

__device__ __forceinline__ unsigned short f2bf(float f) {
  union { float f; unsigned u; } v; v.f = f;
  unsigned r = v.u + 0x7fffu + ((v.u >> 16) & 1u);
  return (unsigned short)(r >> 16);
}

// Abramowitz-Stegun 7.1.26 erf, |eps| <= 1.5e-7; v_rcp (1 ULP) instead of IEEE div
__device__ __forceinline__ float fast_erf(float z) {
  float a = fabsf(z);
  float t = __builtin_amdgcn_rcpf(1.0f + 0.3275911f * a);
  float y = t * (0.254829592f + t * (-0.284496736f + t * (1.421413741f +
            t * (-1.453152027f + t * 1.061405429f))));
  float r = 1.0f - y * __expf(-a * a);
  return z < 0.0f ? -r : r;
}

// ---------------- fused prep: gate (blocks 0..511) + weight transpose (512..1023) ----------
__global__ __launch_bounds__(256) void prep_kernel(
    const float* __restrict__ x, const float* __restrict__ wg,
    const float* __restrict__ bg, const float* __restrict__ w1,
    const float* __restrict__ w2, int* __restrict__ counts,
    int* __restrict__ rows, unsigned short* __restrict__ w1T,
    unsigned short* __restrict__ w2T) {
  __shared__ __align__(16) char smem[50816];
  int tid = threadIdx.x;

  if (blockIdx.x >= 512) {
    // ---- 64x64 fp32 tile transpose -> bf16 ----
    float (*tile)[65] = (float (*)[65])smem;
    int tp = blockIdx.x - 512;
    const float* src; unsigned short* dst; int S, Sd;
    if (tp < 256) {
      int e = tp >> 4, t2 = tp & 15;
      int d0 = (t2 >> 3) * 64, h0 = (t2 & 7) * 64;
      src = w1 + (size_t)e * DD * HH + (size_t)d0 * HH + h0; S = HH;
      dst = w1T + (size_t)e * HH * DD + (size_t)h0 * DD + d0; Sd = DD;
    } else {
      int t = tp - 256;
      int e = t >> 4, t2 = t & 15;
      int h0 = (t2 >> 1) * 64, d0 = (t2 & 1) * 64;
      src = w2 + (size_t)e * HH * DD + (size_t)h0 * DD + d0; S = DD;
      dst = w2T + (size_t)e * DD * HH + (size_t)d0 * HH + h0; Sd = HH;
    }
    #pragma unroll
    for (int i = 0; i < 4; ++i) {
      int u = tid + i * 256, r = u >> 4, c = (u & 15) * 4;
      float4 v = *(const float4*)(src + (size_t)r * S + c);
      tile[r][c + 0] = v.x; tile[r][c + 1] = v.y;
      tile[r][c + 2] = v.z; tile[r][c + 3] = v.w;
    }
    __syncthreads();
    #pragma unroll
    for (int i = 0; i < 4; ++i) {
      int u = tid + i * 256, tr = u >> 4, tc = (u & 15) * 4;
      ushort4 p;
      p.x = f2bf(tile[tc + 0][tr]); p.y = f2bf(tile[tc + 1][tr]);
      p.z = f2bf(tile[tc + 2][tr]); p.w = f2bf(tile[tc + 3][tr]);
      *(ushort4*)(dst + (size_t)tr * Sd + tc) = p;
    }
    return;
  }

  // ---- gating: fp64 logits + block-aggregated bucket scatter ----
  float  (*sx)[132] = (float (*)[132])smem;
  double (*swg)[EE] = (double (*)[EE])(smem + 33792);
  int* lcnt  = (int*)(smem + 50176);
  int* gbase = lcnt + EE;
  int* lslot = gbase + EE;
  int* lexp  = lslot + 64;

  int base = blockIdx.x * 64;
  if (tid < EE) lcnt[tid] = 0;
  for (int i = tid; i < DD * EE; i += 256) swg[i >> 4][i & 15] = (double)wg[i];
  {
    int r = tid >> 2, c0 = (tid & 3) * 32;
    const float4* src = (const float4*)(x + (size_t)(base + r) * DD + c0);
    #pragma unroll
    for (int i = 0; i < 8; ++i)
      *(float4*)&sx[r][c0 + i * 4] = src[i];
  }
  __syncthreads();

  int r = tid >> 2;
  int e0 = (tid & 3) * 4;
  double acc[4];
  #pragma unroll
  for (int j = 0; j < 4; ++j) acc[j] = (double)bg[e0 + j];

  #pragma unroll 4
  for (int d = 0; d < DD; ++d) {
    double xv = (double)sx[r][d];
    #pragma unroll
    for (int j = 0; j < 4; ++j)
      acc[j] += xv * swg[d][e0 + j];
  }

  int beste = 0; double bestv = acc[0];
  #pragma unroll
  for (int j = 1; j < 4; ++j)
    if (acc[j] > bestv) { bestv = acc[j]; beste = j; }
  int ge = e0 + beste;

  #pragma unroll
  for (int off = 1; off < 4; off <<= 1) {
    double ov = __shfl_xor(bestv, off);
    int oe = __shfl_xor(ge, off);
    if (ov > bestv || (ov == bestv && oe < ge)) { bestv = ov; ge = oe; }
  }

  if ((tid & 3) == 0) {
    lslot[r] = atomicAdd(&lcnt[ge], 1);
    lexp[r] = ge;
  }
  __syncthreads();
  if (tid < EE && lcnt[tid] > 0)
    gbase[tid] = atomicAdd(&counts[tid], lcnt[tid]);
  __syncthreads();
  if ((tid & 3) == 0) {
    int e2 = lexp[r];
    rows[e2 * NB + gbase[e2] + lslot[r]] = base + r;
  }
}

// ---------------- grouped expert GEMM: out[r] = gelu(x[r]@w1[e]) @ w2[e] ----------------
// v5: weight staging via __builtin_amdgcn_global_load_lds (width 16) -- zero staging VGPRs,
//     so nothing for the allocator to sink (R2) or spill (R3: +35MB scratch WRITE_SIZE).
//     LDS dest is LINEAR; the XOR swizzle lives in the pre-swizzled GLOBAL source address
//     (same involution slot^=row&7 on both sides -> read algebra identical to R2/R3).
//     One barrier per chunk: stage(next) -> compute(cur) -> barrier (vmcnt drains after a
//     full compute phase of flight time).
// Layout invariant: element (row, col) of a [R][C]-short tile sits at short-index
//   row*C + ((col>>3) ^ (row&7))*8 + (col&7),  C=128 (sW1), C=64 (sW2).
__global__ __launch_bounds__(256, 2) void moe_gemm(
    const float* __restrict__ x, const unsigned short* __restrict__ w1T,
    const unsigned short* __restrict__ w2T, const int* __restrict__ counts,
    const int* __restrict__ rows, float* __restrict__ out) {
  int e = blockIdx.x;
  int cnt = counts[e];
  int base = blockIdx.y * TM;
  if (base >= cnt) return;

  __shared__ unsigned short sW1[2][HC * DD];  // [h][d] swizzled, 16 KB each
  __shared__ unsigned short sW2[2][DD * HC];  // [d][h] swizzled, 16 KB each
  __shared__ unsigned short sH[TM][72];       // [m][h] padded, wave-private rows, 9 KB

  int tid = threadIdx.x;
  int wv = tid >> 6, l = tid & 63;
  int lm = l & 15, q = l >> 4;

  const unsigned short* w1e = w1T + (size_t)e * HH * DD;
  const unsigned short* w2e = w2T + (size_t)e * DD * HH;

  // X A-fragments in registers: xa[ks] holds X[m][k = ks*32 + q*8 + j]
  short8 xa[4];
  {
    int ridx = base + wv * 16 + lm; if (ridx >= cnt) ridx = cnt - 1;
    int grow = rows[e * NB + ridx];
    const float* xr = x + (size_t)grow * DD + q * 8;
    #pragma unroll
    for (int ks = 0; ks < 4; ++ks) {
      f32x4 v0 = *(const f32x4*)(xr + ks * 32);
      f32x4 v1 = *(const f32x4*)(xr + ks * 32 + 4);
      short8 a;
      a[0] = f2bf(v0[0]); a[1] = f2bf(v0[1]); a[2] = f2bf(v0[2]); a[3] = f2bf(v0[3]);
      a[4] = f2bf(v1[0]); a[5] = f2bf(v1[1]); a[6] = f2bf(v1[2]); a[7] = f2bf(v1[3]);
      xa[ks] = a;
    }
  }

  // ---- direct-to-LDS staging of one chunk (sW1: 16KB, sW2: 16KB) ----
  // lane l of wave wv, call i covers LDS shorts [wv*2048 + i*512 + l*8, +8)
  // sW1: row = wv*16 + i*4 + (l>>4), src slot = (l&15) ^ (row&7)
  // sW2: row = wv*32 + i*8 + (l>>3), src slot = (l&7)  ^ (row&7)
  auto stage_chunk = [&](int buf, int c) {
    const unsigned short* w1c = w1e + (size_t)c * HC * DD;
    const unsigned short* w2c = w2e + (size_t)c * HC;
    #pragma unroll
    for (int i = 0; i < 4; ++i) {
      int r = wv * 16 + i * 4 + (l >> 4);
      const unsigned short* g = w1c + (size_t)r * DD + (((l & 15) ^ (r & 7)) << 3);
      __builtin_amdgcn_global_load_lds((gc_us*)g,
          (lds_us*)(&sW1[buf][wv * 2048 + i * 512]), 16, 0, 0);
    }
    #pragma unroll
    for (int i = 0; i < 4; ++i) {
      int r = wv * 32 + i * 8 + (l >> 3);
      const unsigned short* g = w2c + (size_t)r * HH + (((l & 7) ^ (r & 7)) << 3);
      __builtin_amdgcn_global_load_lds((gc_us*)g,
          (lds_us*)(&sW2[buf][wv * 2048 + i * 512]), 16, 0, 0);
    }
  };

  stage_chunk(0, 0);
  __syncthreads();

  f32x4 acc2[8];
  #pragma unroll
  for (int n = 0; n < 8; ++n) acc2[n] = (f32x4){0.f, 0.f, 0.f, 0.f};

  for (int hc = 0; hc < NCH; ++hc) {
    int b = hc & 1;

    // issue next chunk's direct-to-LDS loads into the other buffer (in flight all chunk)
    if (hc + 1 < NCH) stage_chunk(b ^ 1, hc + 1);

    // GEMM1: hidden(16x64 per wave) = X(16x128, regs) @ W1chunk(128x64)
    f32x4 acc1[4];
    #pragma unroll
    for (int n = 0; n < 4; ++n) acc1[n] = (f32x4){0.f, 0.f, 0.f, 0.f};
    #pragma unroll
    for (int ks = 0; ks < 4; ++ks) {
      #pragma unroll
      for (int n = 0; n < 4; ++n) {
        int row = n * 16 + lm;
        int sl = ((ks * 4 + q) ^ (row & 7)) * 8;
        short8 bfr = *(const short8*)&sW1[b][row * DD + sl];
        acc1[n] = __builtin_amdgcn_mfma_f32_16x16x32_bf16(xa[ks], bfr, acc1[n], 0, 0, 0);
      }
    }
    // gelu -> bf16 -> sH (wave-private rows; same-wave lgkmcnt orders RAW)
    #pragma unroll
    for (int n = 0; n < 4; ++n) {
      #pragma unroll
      for (int rr = 0; rr < 4; ++rr) {
        float v = acc1[n][rr];
        float g = 0.5f * v * (1.0f + fast_erf(v * 0.70710678118654752f));
        sH[wv * 16 + q * 4 + rr][n * 16 + lm] = f2bf(g);
      }
    }
    // GEMM2: out(16x128 per wave) += H(16x64) @ W2chunk(64x128)
    #pragma unroll
    for (int ks = 0; ks < 2; ++ks) {
      int kk = ks * 32 + q * 8;
      short8 a = *(const short8*)&sH[wv * 16 + lm][kk];
      #pragma unroll
      for (int n = 0; n < 8; ++n) {
        int row = n * 16 + lm;
        int sl = ((ks * 4 + q) ^ (row & 7)) * 8;
        short8 bfr = *(const short8*)&sW2[b][row * HC + sl];
        acc2[n] = __builtin_amdgcn_mfma_f32_16x16x32_bf16(a, bfr, acc2[n], 0, 0, 0);
      }
    }

    __syncthreads();  // drains staging vmcnt (full compute phase in flight) + releases buf b
  }

  // epilogue: scatter rows (score == 1.0 for top-1 softmax)
  #pragma unroll
  for (int rr = 0; rr < 4; ++rr) {
    int ml = wv * 16 + q * 4 + rr;
    int ridx = base + ml;
    if (ridx < cnt) {
      int grow = rows[e * NB + ridx];
      float* op = out + (size_t)grow * DD + lm;
      #pragma unroll
      for (int n = 0; n < 8; ++n) op[n * 16] = acc2[n][rr];
    }
  }
}

extern "C" void kernel_launch(void* const* d_in, const int* in_sizes, int n_in,
                              void* d_out, int out_size, void* d_ws, size_t ws_size,
                              hipStream_t stream) {
  const float* x  = (const float*)d_in[0];
  const float* w1 = (const float*)d_in[1];
  const float* w2 = (const float*)d_in[2];
  const float* wg = (const float*)d_in[3];
  const float* bg = (const float*)d_in[4];
  float* out = (float*)d_out;

  // workspace: [0,64) counts ; [1024, +2MB) rows ; w1T bf16 2MB ; w2T bf16 2MB
  int* counts = (int*)d_ws;
  int* rows   = (int*)((char*)d_ws + 1024);
  unsigned short* w1T = (unsigned short*)((char*)d_ws + 1024 + (size_t)EE * NB * 4);
  unsigned short* w2T = w1T + (size_t)EE * HH * DD;

  hipMemsetAsync(d_ws, 0, 64, stream);
  hipLaunchKernelGGL(prep_kernel, dim3(1024), dim3(256), 0, stream,
                     x, wg, bg, w1, w2, counts, rows, w1T, w2T);
  hipLaunchKernelGGL(moe_gemm, dim3(EE, NB / TM), dim3(256), 0, stream,
                     x, w1T, w2T, counts, rows, out);
}

// Round 5
// 129.512 us; speedup vs baseline: 1.3190x; 1.0441x over previous
//
#include <hip/hip_runtime.h>
#include <hip/hip_bf16.h>
#include <math.h>

#define NB 32768
#define DD 128
#define HH 512
#define EE 16
#define TM 32
#define HC 64
#define NCH (HH / HC)

typedef __attribute__((ext_vector_type(8))) short short8;
typedef __attribute__((ext_vector_type(4))) float f32x4;
typedef __attribute__((address_space(1))) const unsigned short gc_us;
typedef __attribute__((address_space(3))) unsigned short lds_us;

__device__ __forceinline__ unsigned short f2bf(float f) {
  union { float f; unsigned u; } v; v.f = f;
  unsigned r = v.u + 0x7fffu + ((v.u >> 16) & 1u);
  return (unsigned short)(r >> 16);
}

// Abramowitz-Stegun 7.1.26 erf, |eps| <= 1.5e-7; v_rcp (1 ULP) instead of IEEE div
__device__ __forceinline__ float fast_erf(float z) {
  float a = fabsf(z);
  float t = __builtin_amdgcn_rcpf(1.0f + 0.3275911f * a);
  float y = t * (0.254829592f + t * (-0.284496736f + t * (1.421413741f +
            t * (-1.453152027f + t * 1.061405429f))));
  float r = 1.0f - y * __expf(-a * a);
  return z < 0.0f ? -r : r;
}

// ---------------- fused prep: gate (blocks 0..511) + weight transpose (512..1023) ----------
__global__ __launch_bounds__(256) void prep_kernel(
    const float* __restrict__ x, const float* __restrict__ wg,
    const float* __restrict__ bg, const float* __restrict__ w1,
    const float* __restrict__ w2, int* __restrict__ counts,
    int* __restrict__ rows, unsigned short* __restrict__ w1T,
    unsigned short* __restrict__ w2T) {
  __shared__ __align__(16) char smem[50816];
  int tid = threadIdx.x;

  if (blockIdx.x >= 512) {
    // ---- 64x64 fp32 tile transpose -> bf16 ----
    float (*tile)[65] = (float (*)[65])smem;
    int tp = blockIdx.x - 512;
    const float* src; unsigned short* dst; int S, Sd;
    if (tp < 256) {
      int e = tp >> 4, t2 = tp & 15;
      int d0 = (t2 >> 3) * 64, h0 = (t2 & 7) * 64;
      src = w1 + (size_t)e * DD * HH + (size_t)d0 * HH + h0; S = HH;
      dst = w1T + (size_t)e * HH * DD + (size_t)h0 * DD + d0; Sd = DD;
    } else {
      int t = tp - 256;
      int e = t >> 4, t2 = t & 15;
      int h0 = (t2 >> 1) * 64, d0 = (t2 & 1) * 64;
      src = w2 + (size_t)e * HH * DD + (size_t)h0 * DD + d0; S = DD;
      dst = w2T + (size_t)e * DD * HH + (size_t)d0 * HH + h0; Sd = HH;
    }
    #pragma unroll
    for (int i = 0; i < 4; ++i) {
      int u = tid + i * 256, r = u >> 4, c = (u & 15) * 4;
      float4 v = *(const float4*)(src + (size_t)r * S + c);
      tile[r][c + 0] = v.x; tile[r][c + 1] = v.y;
      tile[r][c + 2] = v.z; tile[r][c + 3] = v.w;
    }
    __syncthreads();
    #pragma unroll
    for (int i = 0; i < 4; ++i) {
      int u = tid + i * 256, tr = u >> 4, tc = (u & 15) * 4;
      ushort4 p;
      p.x = f2bf(tile[tc + 0][tr]); p.y = f2bf(tile[tc + 1][tr]);
      p.z = f2bf(tile[tc + 2][tr]); p.w = f2bf(tile[tc + 3][tr]);
      *(ushort4*)(dst + (size_t)tr * Sd + tc) = p;
    }
    return;
  }

  // ---- gating: fp64 logits + block-aggregated bucket scatter ----
  float  (*sx)[132] = (float (*)[132])smem;
  double (*swg)[EE] = (double (*)[EE])(smem + 33792);
  int* lcnt  = (int*)(smem + 50176);
  int* gbase = lcnt + EE;
  int* lslot = gbase + EE;
  int* lexp  = lslot + 64;

  int base = blockIdx.x * 64;
  if (tid < EE) lcnt[tid] = 0;
  for (int i = tid; i < DD * EE; i += 256) swg[i >> 4][i & 15] = (double)wg[i];
  {
    int r = tid >> 2, c0 = (tid & 3) * 32;
    const float4* src = (const float4*)(x + (size_t)(base + r) * DD + c0);
    #pragma unroll
    for (int i = 0; i < 8; ++i)
      *(float4*)&sx[r][c0 + i * 4] = src[i];
  }
  __syncthreads();

  int r = tid >> 2;
  int e0 = (tid & 3) * 4;
  double acc[4];
  #pragma unroll
  for (int j = 0; j < 4; ++j) acc[j] = (double)bg[e0 + j];

  #pragma unroll 4
  for (int d = 0; d < DD; ++d) {
    double xv = (double)sx[r][d];
    #pragma unroll
    for (int j = 0; j < 4; ++j)
      acc[j] += xv * swg[d][e0 + j];
  }

  int beste = 0; double bestv = acc[0];
  #pragma unroll
  for (int j = 1; j < 4; ++j)
    if (acc[j] > bestv) { bestv = acc[j]; beste = j; }
  int ge = e0 + beste;

  #pragma unroll
  for (int off = 1; off < 4; off <<= 1) {
    double ov = __shfl_xor(bestv, off);
    int oe = __shfl_xor(ge, off);
    if (ov > bestv || (ov == bestv && oe < ge)) { bestv = ov; ge = oe; }
  }

  if ((tid & 3) == 0) {
    lslot[r] = atomicAdd(&lcnt[ge], 1);
    lexp[r] = ge;
  }
  __syncthreads();
  if (tid < EE && lcnt[tid] > 0)
    gbase[tid] = atomicAdd(&counts[tid], lcnt[tid]);
  __syncthreads();
  if ((tid & 3) == 0) {
    int e2 = lexp[r];
    rows[e2 * NB + gbase[e2] + lslot[r]] = base + r;
  }
}

// ---------------- grouped expert GEMM: out[r] = gelu(x[r]@w1[e]) @ w2[e] ----------------
// v6: occupancy restructure. Wave = (row-group rg, H-half hf): each wave runs GEMM1 for its
//     32-h half, gelu into a WAVE-PRIVATE sH region, GEMM2 over its own k-half (partial
//     acc2), one epilogue LDS exchange sums the halves. Per-wave work halves -> TM=32,
//     1024 useful blocks, 4 blocks/CU (37.9 KB LDS, single-buffered weights), 16 waves/CU
//     = 2x latency hiding + 4 independent barrier groups (was 2 lockstep groups).
//     Staging geometry/swizzle byte-identical to verified v5.
// Layout invariant: element (row, col) of a [R][C]-short tile sits at short-index
//   row*C + ((col>>3) ^ (row&7))*8 + (col&7),  C=128 (sW1), C=64 (sW2).
__global__ __launch_bounds__(256, 4) void moe_gemm(
    const float* __restrict__ x, const unsigned short* __restrict__ w1T,
    const unsigned short* __restrict__ w2T, const int* __restrict__ counts,
    const int* __restrict__ rows, float* __restrict__ out) {
  int e = blockIdx.x;
  int cnt = counts[e];
  int base = blockIdx.y * TM;
  if (base >= cnt) return;

  __shared__ __align__(16) unsigned short sW1[HC * DD];  // [h][d] swizzled, 16 KB
  __shared__ __align__(16) unsigned short sW2[DD * HC];  // [d][h] swizzled, 16 KB
  __shared__ __align__(16) unsigned short sH[TM * 80];   // [m][h] pad-80, wave-private, 5 KB

  int tid = threadIdx.x;
  int wv = tid >> 6, l = tid & 63;
  int lm = l & 15, q = l >> 4;
  int rg = wv & 1;       // row group: rows [rg*16, rg*16+16)
  int hf = wv >> 1;      // H half:    h in [hf*32, hf*32+32) of each chunk

  const unsigned short* w1e = w1T + (size_t)e * HH * DD;
  const unsigned short* w2e = w2T + (size_t)e * DD * HH;

  // X A-fragments in registers: xa[ks] holds X[m = rg*16+lm][k = ks*32 + q*8 + j]
  short8 xa[4];
  {
    int ridx = base + rg * 16 + lm; if (ridx >= cnt) ridx = cnt - 1;
    int grow = rows[e * NB + ridx];
    const float* xr = x + (size_t)grow * DD + q * 8;
    #pragma unroll
    for (int ks = 0; ks < 4; ++ks) {
      f32x4 v0 = *(const f32x4*)(xr + ks * 32);
      f32x4 v1 = *(const f32x4*)(xr + ks * 32 + 4);
      short8 a;
      a[0] = f2bf(v0[0]); a[1] = f2bf(v0[1]); a[2] = f2bf(v0[2]); a[3] = f2bf(v0[3]);
      a[4] = f2bf(v1[0]); a[5] = f2bf(v1[1]); a[6] = f2bf(v1[2]); a[7] = f2bf(v1[3]);
      xa[ks] = a;
    }
  }

  f32x4 acc2[8];
  #pragma unroll
  for (int n = 0; n < 8; ++n) acc2[n] = (f32x4){0.f, 0.f, 0.f, 0.f};

  for (int hc = 0; hc < NCH; ++hc) {
    // ---- stage chunk hc direct-to-LDS (v5-verified geometry; wave-uniform LDS base) ----
    {
      const unsigned short* w1c = w1e + (size_t)hc * HC * DD;
      const unsigned short* w2c = w2e + (size_t)hc * HC;
      #pragma unroll
      for (int i = 0; i < 4; ++i) {
        int r = wv * 16 + i * 4 + (l >> 4);
        const unsigned short* g = w1c + (size_t)r * DD + (((l & 15) ^ (r & 7)) << 3);
        __builtin_amdgcn_global_load_lds((gc_us*)g,
            (lds_us*)(&sW1[wv * 2048 + i * 512]), 16, 0, 0);
      }
      #pragma unroll
      for (int i = 0; i < 4; ++i) {
        int r = wv * 32 + i * 8 + (l >> 3);
        const unsigned short* g = w2c + (size_t)r * HH + (((l & 7) ^ (r & 7)) << 3);
        __builtin_amdgcn_global_load_lds((gc_us*)g,
            (lds_us*)(&sW2[wv * 2048 + i * 512]), 16, 0, 0);
      }
    }
    __syncthreads();   // drains vmcnt (DMA landed); other resident blocks compute meanwhile

    // GEMM1: hidden(16 rows x 32 h per wave) = X(16x128, regs) @ W1chunk[:, hf-half]
    f32x4 acc1[2];
    #pragma unroll
    for (int n = 0; n < 2; ++n) acc1[n] = (f32x4){0.f, 0.f, 0.f, 0.f};
    #pragma unroll
    for (int ks = 0; ks < 4; ++ks) {
      #pragma unroll
      for (int n = 0; n < 2; ++n) {
        int row = hf * 32 + n * 16 + lm;
        int sl = ((ks * 4 + q) ^ (row & 7)) * 8;
        short8 bfr = *(const short8*)&sW1[row * DD + sl];
        acc1[n] = __builtin_amdgcn_mfma_f32_16x16x32_bf16(xa[ks], bfr, acc1[n], 0, 0, 0);
      }
    }
    // gelu -> bf16 -> sH (wave-private region: rows rg*16.., cols hf*32..; lgkmcnt orders RAW)
    #pragma unroll
    for (int n = 0; n < 2; ++n) {
      #pragma unroll
      for (int rr = 0; rr < 4; ++rr) {
        float v = acc1[n][rr];
        float g = 0.5f * v * (1.0f + fast_erf(v * 0.70710678118654752f));
        sH[(rg * 16 + q * 4 + rr) * 80 + hf * 32 + n * 16 + lm] = f2bf(g);
      }
    }
    // GEMM2 partial: out(16x128 per wave) += H(16 x 32-k half) @ W2chunk[hf-half, :]
    {
      short8 a = *(const short8*)&sH[(rg * 16 + lm) * 80 + hf * 32 + q * 8];
      #pragma unroll
      for (int n = 0; n < 8; ++n) {
        int row = n * 16 + lm;
        int sl = ((hf * 4 + q) ^ (row & 7)) * 8;
        short8 bfr = *(const short8*)&sW2[row * HC + sl];
        acc2[n] = __builtin_amdgcn_mfma_f32_16x16x32_bf16(a, bfr, acc2[n], 0, 0, 0);
      }
    }
    __syncthreads();   // all waves done reading sW1/sW2 before next chunk's DMA overwrites
  }

  // ---- epilogue: sum H-half partials (LDS exchange, once) then scatter rows ----
  float* sc = (rg == 0) ? (float*)sW1 : (float*)sW2;   // [16][132] fp32 scratch per row-group
  if (hf == 1) {
    #pragma unroll
    for (int n = 0; n < 8; ++n)
      #pragma unroll
      for (int rr = 0; rr < 4; ++rr)
        sc[(q * 4 + rr) * 132 + n * 16 + lm] = acc2[n][rr];
  }
  __syncthreads();
  if (hf == 0) {
    #pragma unroll
    for (int rr = 0; rr < 4; ++rr) {
      int ml = rg * 16 + q * 4 + rr;
      int ridx = base + ml;
      if (ridx < cnt) {
        int grow = rows[e * NB + ridx];
        float* op = out + (size_t)grow * DD + lm;
        #pragma unroll
        for (int n = 0; n < 8; ++n)
          op[n * 16] = acc2[n][rr] + sc[(q * 4 + rr) * 132 + n * 16 + lm];
      }
    }
  }
}

extern "C" void kernel_launch(void* const* d_in, const int* in_sizes, int n_in,
                              void* d_out, int out_size, void* d_ws, size_t ws_size,
                              hipStream_t stream) {
  const float* x  = (const float*)d_in[0];
  const float* w1 = (const float*)d_in[1];
  const float* w2 = (const float*)d_in[2];
  const float* wg = (const float*)d_in[3];
  const float* bg = (const float*)d_in[4];
  float* out = (float*)d_out;

  // workspace: [0,64) counts ; [1024, +2MB) rows ; w1T bf16 2MB ; w2T bf16 2MB
  int* counts = (int*)d_ws;
  int* rows   = (int*)((char*)d_ws + 1024);
  unsigned short* w1T = (unsigned short*)((char*)d_ws + 1024 + (size_t)EE * NB * 4);
  unsigned short* w2T = w1T + (size_t)EE * HH * DD;

  hipMemsetAsync(d_ws, 0, 64, stream);
  hipLaunchKernelGGL(prep_kernel, dim3(1024), dim3(256), 0, stream,
                     x, wg, bg, w1, w2, counts, rows, w1T, w2T);
  hipLaunchKernelGGL(moe_gemm, dim3(EE, NB / TM), dim3(256), 0, stream,
                     x, w1T, w2T, counts, rows, out);
}